// Round 4
// baseline (93.121 us; speedup 1.0000x reference)
//
#include <hip/hip_runtime.h>
#include <math.h>

#define NROWS 4096
#define DDIM  256
#define BM 256
#define BN 256
#define BK 64
#define LOG2E2 2.8853900817779268f   // 2*log2(e): exp(2S) = exp2(LOG2E2 * S)

typedef __attribute__((ext_vector_type(8))) short short8;  // 8 bf16 (4 VGPRs)
typedef __attribute__((ext_vector_type(4))) float f32x4;   // MFMA 16x16 C/D

__device__ __forceinline__ unsigned short f2bf(float f) {  // RNE float->bf16
    unsigned int u = __float_as_uint(f);
    u += 0x7fffu + ((u >> 16) & 1u);
    return (unsigned short)(u >> 16);
}

__device__ __forceinline__ float exp2_fast(float x) {
#if __has_builtin(__builtin_amdgcn_exp2f)
    return __builtin_amdgcn_exp2f(x);
#else
    return exp2f(x);
#endif
}

// global -> LDS direct DMA, 16B per lane. LDS dest is wave-uniform base
// (lane offset implicit +lane*16); global src is per-lane (pre-swizzled).
#define GLOAD_LDS16(gsrc, ldst)                                          \
    __builtin_amdgcn_global_load_lds(                                    \
        (__attribute__((address_space(1))) void*)(gsrc),                 \
        (__attribute__((address_space(3))) void*)(ldst), 16, 0, 0)

// ---------------- Kernel 1: L2-normalize rows + positive dots ----------------
// 1 wave per row. pos computed in fp32 (exact); bf16 copies written for MFMA.
// A-side (zi) pre-scaled by 2*log2(e) so the GEMM accumulator is exp2-ready.
__global__ __launch_bounds__(256) void normalize_kernel(
    const float* __restrict__ emb_i, const float* __restrict__ emb_j,
    unsigned short* __restrict__ zi, unsigned short* __restrict__ zj,
    float* __restrict__ pos)
{
    const int wave = threadIdx.x >> 6;
    const int lane = threadIdx.x & 63;
    const int row  = blockIdx.x * 4 + wave;

    const float4 vi = *((const float4*)(emb_i + (size_t)row * DDIM) + lane);
    const float4 vj = *((const float4*)(emb_j + (size_t)row * DDIM) + lane);

    float ssi = vi.x*vi.x + vi.y*vi.y + vi.z*vi.z + vi.w*vi.w;
    float ssj = vj.x*vj.x + vj.y*vj.y + vj.z*vj.z + vj.w*vj.w;
    #pragma unroll
    for (int m = 1; m < 64; m <<= 1) {
        ssi += __shfl_xor(ssi, m);
        ssj += __shfl_xor(ssj, m);
    }
    const float ri = 1.0f / fmaxf(sqrtf(ssi), 1e-12f);
    const float rj = 1.0f / fmaxf(sqrtf(ssj), 1e-12f);

    const float zix = vi.x*ri, ziy = vi.y*ri, ziz = vi.z*ri, ziw = vi.w*ri;
    const float zjx = vj.x*rj, zjy = vj.y*rj, zjz = vj.z*rj, zjw = vj.w*rj;

    float p = zix*zjx + ziy*zjy + ziz*zjz + ziw*zjw;
    #pragma unroll
    for (int m = 1; m < 64; m <<= 1) p += __shfl_xor(p, m);
    if (lane == 0) pos[row] = p;

    ushort4 oi = { f2bf(zix*LOG2E2), f2bf(ziy*LOG2E2), f2bf(ziz*LOG2E2), f2bf(ziw*LOG2E2) };
    ushort4 oj = { f2bf(zjx), f2bf(zjy), f2bf(zjz), f2bf(zjw) };
    *((ushort4*)(zi + (size_t)row * DDIM) + lane) = oi;
    *((ushort4*)(zj + (size_t)row * DDIM) + lane) = oj;
}

// ---------- Kernel 2: bf16 MFMA S-tile + exp2 + row/col partial sums ----------
// 256x256 tile, 8 waves (2 row-halves x 4 col-quarters), each wave 128x64 out
// = 8x4 frags of 16x16x32 MFMA. Double-buffered LDS (2x(A+B) = 128 KiB),
// 2-phase: issue next K-tile's global_load_lds BEFORE current ds_read+MFMA,
// single vmcnt-drain barrier per tile. XOR-swizzle (byte ^= (row&7)<<4)
// applied on pre-swizzled global SOURCE and on the ds_read (rule #21).
__global__ __launch_bounds__(512) void gemm_fused_kernel(
    const unsigned short* __restrict__ zi, const unsigned short* __restrict__ zj,
    float* __restrict__ rowsum, float* __restrict__ colsum)
{
    __shared__ unsigned short As[2][BM * BK];   // 64 KiB
    __shared__ unsigned short Bs[2][BM * BK];   // 64 KiB

    const int tid  = threadIdx.x;
    const int lane = tid & 63;
    const int wave = tid >> 6;     // 0..7
    const int g    = lane >> 4;    // k-group 0..3
    const int fr   = lane & 15;    // fragment row 0..15
    const int wr   = wave >> 2;    // wave row-half 0..1
    const int wc   = wave & 3;     // wave col-quarter 0..3
    const int bm   = blockIdx.x * BM;
    const int bn   = blockIdx.y * BN;

    f32x4 acc[8][4] = {};          // all indices compile-time (rule #20)

    // Staging geometry: per round `it`, thread covers LDS linear slot
    // (it*512+tid)*16B -> row = it*64 + (tid>>3), lds slot = tid&7.
    // Source column slot = ldsslot ^ (row&7)  (same involution as the read).
    const int srow0 = tid >> 3;                              // 0..63
    const int soff  = (((tid & 7) ^ (srow0 & 7)) << 3);      // ushort offset

    auto stage = [&](int buf, int k0) {
        #pragma unroll
        for (int it = 0; it < 4; ++it) {
            const int row = it * 64 + srow0;
            const int lb  = (it * 512 + wave * 64) << 3;     // wave-uniform, ushorts
            GLOAD_LDS16(zi + (size_t)(bm + row) * DDIM + k0 + soff, &As[buf][lb]);
            GLOAD_LDS16(zj + (size_t)(bn + row) * DDIM + k0 + soff, &Bs[buf][lb]);
        }
    };

    auto compute = [&](int buf) {
        #pragma unroll
        for (int kk = 0; kk < 2; ++kk) {
            const int coff = (((kk * 4 + g) ^ (fr & 7)) << 3);
            short8 a[8], b[4];
            #pragma unroll
            for (int mi = 0; mi < 8; ++mi)
                a[mi] = *(const short8*)&As[buf][(wr * 128 + mi * 16 + fr) * BK + coff];
            #pragma unroll
            for (int ni = 0; ni < 4; ++ni)
                b[ni] = *(const short8*)&Bs[buf][(wc * 64 + ni * 16 + fr) * BK + coff];
            #pragma unroll
            for (int mi = 0; mi < 8; ++mi)
                #pragma unroll
                for (int ni = 0; ni < 4; ++ni)
                    acc[mi][ni] = __builtin_amdgcn_mfma_f32_16x16x32_bf16(
                        a[mi], b[ni], acc[mi][ni], 0, 0, 0);
        }
    };

    stage(0, 0);
    __syncthreads();            // drain prologue staging
    stage(1, BK);               // prefetch tile 1
    compute(0);
    __syncthreads();            // drains vmcnt (tile 1) + lgkm, frees buf 0
    stage(0, 2 * BK);           // prefetch tile 2
    compute(1);
    __syncthreads();
    stage(1, 3 * BK);           // prefetch tile 3
    compute(0);
    __syncthreads();
    compute(1);                 // last tile, no trailing barrier needed

    // Epilogue. acc[mi][ni][j] = LOG2E2 * S at row bm+wr*128+mi*16+g*4+j,
    // col bn+wc*64+ni*16+fr (C/D layout verified absmax=0 in R3).
    float cp[4] = {0.f, 0.f, 0.f, 0.f};
    #pragma unroll
    for (int mi = 0; mi < 8; ++mi) {
        float rpj[4] = {0.f, 0.f, 0.f, 0.f};
        #pragma unroll
        for (int ni = 0; ni < 4; ++ni)
            #pragma unroll
            for (int j = 0; j < 4; ++j) {
                const float e = exp2_fast(acc[mi][ni][j]);
                rpj[j]  += e;
                cp[ni]  += e;
            }
        // Row sums: reduce over cols = lane bits 0..3.
        #pragma unroll
        for (int j = 0; j < 4; ++j) {
            float v = rpj[j];
            v += __shfl_xor(v, 1); v += __shfl_xor(v, 2);
            v += __shfl_xor(v, 4); v += __shfl_xor(v, 8);
            if (fr == 0)
                atomicAdd(&rowsum[bm + wr * 128 + mi * 16 + g * 4 + j], v);
        }
    }
    // Col sums: reduce over row-groups = lane bits 4,5.
    #pragma unroll
    for (int ni = 0; ni < 4; ++ni) {
        float v = cp[ni];
        v += __shfl_xor(v, 16); v += __shfl_xor(v, 32);
        if (g == 0)
            atomicAdd(&colsum[bn + wc * 64 + ni * 16 + fr], v);
    }
}

// ---------------- Kernel 3: final loss reduction ----------------
__global__ __launch_bounds__(256) void finalize_kernel(
    const float* __restrict__ pos, const float* __restrict__ rowsum,
    const float* __restrict__ colsum, float* __restrict__ out)
{
    float s = 0.0f;
    for (int r = threadIdx.x; r < NROWS; r += 256) {
        // log(0.5*a) + log(0.5*b) = log(0.25*a*b)
        s += -4.0f * pos[r] + logf(0.25f * rowsum[r] * colsum[r]);
    }
    __shared__ float part[4];
    #pragma unroll
    for (int m = 1; m < 64; m <<= 1) s += __shfl_xor(s, m);
    if ((threadIdx.x & 63) == 0) part[threadIdx.x >> 6] = s;
    __syncthreads();
    if (threadIdx.x == 0)
        out[0] = (part[0] + part[1] + part[2] + part[3]) / (2.0f * NROWS);
}

extern "C" void kernel_launch(void* const* d_in, const int* in_sizes, int n_in,
                              void* d_out, int out_size, void* d_ws, size_t ws_size,
                              hipStream_t stream)
{
    const float* emb_i = (const float*)d_in[0];
    const float* emb_j = (const float*)d_in[1];

    unsigned short* zi = (unsigned short*)d_ws;               // N*D bf16 (scaled)
    unsigned short* zj = zi + (size_t)NROWS * DDIM;           // N*D bf16
    float* pos    = (float*)(zj + (size_t)NROWS * DDIM);      // N
    float* rowsum = pos + NROWS;                              // N
    float* colsum = rowsum + NROWS;                           // N

    // ws is poisoned 0xAA before every timed launch — zero the accumulators.
    hipMemsetAsync(rowsum, 0, 2 * NROWS * sizeof(float), stream);

    normalize_kernel<<<NROWS / 4, 256, 0, stream>>>(emb_i, emb_j, zi, zj, pos);

    dim3 grid(NROWS / BM, NROWS / BN);   // 16 x 16 = 256 blocks, 1/CU
    gemm_fused_kernel<<<grid, 512, 0, stream>>>(zi, zj, rowsum, colsum);

    finalize_kernel<<<1, 256, 0, stream>>>(pos, rowsum, colsum, (float*)d_out);
}